// Round 3
// baseline (321.644 us; speedup 1.0000x reference)
//
#include <hip/hip_runtime.h>

#define H 1024
#define QD 16
#define BATCH 4
#define SEQ 2048
#define MROWS 8192  // BATCH*SEQ

typedef __bf16 bf16x8 __attribute__((ext_vector_type(8)));
typedef __bf16 bf16x4 __attribute__((ext_vector_type(4)));
typedef float f32x4 __attribute__((ext_vector_type(4)));

__device__ __forceinline__ void async_g2l_16(const void* g, void* l) {
  __builtin_amdgcn_global_load_lds(
      (const __attribute__((address_space(1))) unsigned int*)g,
      (__attribute__((address_space(3))) unsigned int*)l, 16, 0, 0);
}

// ---------------- fp32 -> bf16 hi/lo split (x) ----------------
__global__ __launch_bounds__(256) void cvt_split(const float* __restrict__ src,
                                                 __bf16* __restrict__ hi,
                                                 __bf16* __restrict__ lo, int n) {
  int i = (blockIdx.x * 256 + threadIdx.x) * 4;
  if (i < n) {
    float4 f = *(const float4*)(src + i);
    bf16x4 h, l;
    h[0] = (__bf16)f.x; l[0] = (__bf16)(f.x - (float)h[0]);
    h[1] = (__bf16)f.y; l[1] = (__bf16)(f.y - (float)h[1]);
    h[2] = (__bf16)f.z; l[2] = (__bf16)(f.z - (float)h[2]);
    h[3] = (__bf16)f.w; l[3] = (__bf16)(f.w - (float)h[3]);
    *(bf16x4*)(hi + i) = h;
    *(bf16x4*)(lo + i) = l;
  }
}

// ---------------- fp32 [R][C] -> bf16 transposed [C][R] ----------------
__global__ __launch_bounds__(256) void transpose_cvt_f32_bf16(
    const float* __restrict__ src, __bf16* __restrict__ dst, int R, int C) {
  __shared__ float t[32][33];
  const int rb = blockIdx.y * 32, cb = blockIdx.x * 32;
  const int c = threadIdx.x & 31;
  const int r0 = threadIdx.x >> 5;
#pragma unroll
  for (int rr = r0; rr < 32; rr += 8)
    t[rr][c] = src[(long)(rb + rr) * C + cb + c];
  __syncthreads();
#pragma unroll
  for (int rr = r0; rr < 32; rr += 8)
    dst[(long)(cb + rr) * R + rb + c] = (__bf16)t[c][rr];
}

// ---------------- bf16 [R][C] -> bf16 transposed [C][R], batched ----------------
__global__ __launch_bounds__(256) void transpose_bf16_batched(
    const __bf16* __restrict__ src, __bf16* __restrict__ dst, int R, int C,
    long sS, long sD) {
  __shared__ __bf16 t[32][33];
  const __bf16* s = src + (long)blockIdx.z * sS;
  __bf16* d = dst + (long)blockIdx.z * sD;
  const int rb = blockIdx.y * 32, cb = blockIdx.x * 32;
  const int c = threadIdx.x & 31;
  const int r0 = threadIdx.x >> 5;
#pragma unroll
  for (int rr = r0; rr < 32; rr += 8)
    t[rr][c] = s[(long)(rb + rr) * C + cb + c];
  __syncthreads();
#pragma unroll
  for (int rr = r0; rr < 32; rr += 8)
    d[(long)(cb + rr) * R + rb + c] = t[c][rr];
}

// ---------------- CqkT (Bt layout [32][1024]) in bf16 hi/lo ----------------
__global__ __launch_bounds__(256) void k2_cqk(const float* __restrict__ Wq,
                                              const float* __restrict__ Wk,
                                              const float* __restrict__ We,
                                              __bf16* __restrict__ Cth,
                                              __bf16* __restrict__ Ctl) {
  const int gw = blockIdx.x * 4 + (threadIdx.x >> 6);  // 0..2047
  const int lane = threadIdx.x & 63;
  const int mat = gw & 1, k = gw >> 1;
  const float* Wrow = (mat ? Wk : Wq) + (long)k * H;
  const int col = lane & 15, q4 = lane >> 4;
  float acc = 0.f;
  for (int n0 = 0; n0 < 256; ++n0) {
    int n = q4 * 256 + n0;
    acc += Wrow[n] * We[n * QD + col];
  }
  acc += __shfl_xor(acc, 16);
  acc += __shfl_xor(acc, 32);
  if (lane < 16) {
    __bf16 hi = (__bf16)acc;
    __bf16 lo = (__bf16)(acc - (float)hi);
    long idx = (long)(mat * 16 + col) * H + k;
    Cth[idx] = hi;
    Ctl[idx] = lo;
  }
}

// ---------------- dvec[j] = (bq|bk)@We + be ----------------
__global__ void k2b_dvec(const float* __restrict__ bq, const float* __restrict__ bk,
                         const float* __restrict__ We, const float* __restrict__ be,
                         float* __restrict__ dvec) {
  int j = threadIdx.x;
  if (j < 32) {
    int mat = j >> 4, col = j & 15;
    const float* b = mat ? bk : bq;
    float acc = be[col];
    for (int n = 0; n < H; ++n) acc += b[n] * We[n * QD + col];
    dvec[j] = acc;
  }
}

// ---------------- embed via MFMA (hi/lo split), fused normalize ----------------
// Outputs bf16 qq/kk in [S][32] layout with zero-padded upper K half.
__global__ __launch_bounds__(256) void k3_embed_mfma(
    const __bf16* __restrict__ xh, const __bf16* __restrict__ xl,
    const __bf16* __restrict__ Cth, const __bf16* __restrict__ Ctl,
    const float* __restrict__ dvec, __bf16* __restrict__ qq32,
    __bf16* __restrict__ kk32) {
  __shared__ __bf16 Ah[32 * 64];
  __shared__ __bf16 Al[32 * 64];
  __shared__ __bf16 Bh[32 * 64];
  __shared__ __bf16 Bl[32 * 64];
  const int tid = threadIdx.x;
  const int lane = tid & 63;
  const int w = tid >> 6;
  const int rowhalf = w >> 1;  // 0/1 -> rows 0-15 / 16-31
  const int ntile = w & 1;     // 0 -> qq, 1 -> kk
  const long rowBase = (long)blockIdx.x * 32;

  const int srow = tid >> 3;       // 0..31
  const int skk = (tid & 7) * 8;   // 0,8,..,56
  const __bf16* agh = xh + (rowBase + srow) * H + skk;
  const __bf16* agl = xl + (rowBase + srow) * H + skk;
  const __bf16* bgh = Cth + (long)srow * H + skk;
  const __bf16* bgl = Ctl + (long)srow * H + skk;
  __bf16* lah = &Ah[srow * 64 + skk];
  __bf16* lal = &Al[srow * 64 + skk];
  __bf16* lbh = &Bh[srow * 64 + skk];
  __bf16* lbl = &Bl[srow * 64 + skk];

  f32x4 acc;
  acc[0] = 0.f; acc[1] = 0.f; acc[2] = 0.f; acc[3] = 0.f;
  const int afrag0 = (rowhalf * 16 + (lane & 15)) * 64 + ((lane >> 4) * 8);
  const int bfrag0 = (ntile * 16 + (lane & 15)) * 64 + ((lane >> 4) * 8);

  for (int k0 = 0; k0 < H; k0 += 64) {
    async_g2l_16(agh + k0, lah);
    async_g2l_16(agl + k0, lal);
    async_g2l_16(bgh + k0, lbh);
    async_g2l_16(bgl + k0, lbl);
    __syncthreads();
#pragma unroll
    for (int s = 0; s < 2; ++s) {
      bf16x8 fah = *(const bf16x8*)&Ah[afrag0 + s * 32];
      bf16x8 fal = *(const bf16x8*)&Al[afrag0 + s * 32];
      bf16x8 fbh = *(const bf16x8*)&Bh[bfrag0 + s * 32];
      bf16x8 fbl = *(const bf16x8*)&Bl[bfrag0 + s * 32];
      acc = __builtin_amdgcn_mfma_f32_16x16x32_bf16(fah, fbh, acc, 0, 0, 0);
      acc = __builtin_amdgcn_mfma_f32_16x16x32_bf16(fal, fbh, acc, 0, 0, 0);
      acc = __builtin_amdgcn_mfma_f32_16x16x32_bf16(fah, fbl, acc, 0, 0, 0);
    }
    __syncthreads();
  }

  const float dv = dvec[ntile * 16 + (lane & 15)];
  __bf16* outp = ntile ? kk32 : qq32;
  const int quad = lane >> 4;
#pragma unroll
  for (int r = 0; r < 4; ++r) {
    float z = acc[r] + dv;
    float s2 = z * z;
    s2 += __shfl_xor(s2, 1);
    s2 += __shfl_xor(s2, 2);
    s2 += __shfl_xor(s2, 4);
    s2 += __shfl_xor(s2, 8);
    float val = z * rsqrtf(s2 + 1e-8f);
    long row = rowBase + rowhalf * 16 + quad * 4 + r;
    outp[row * 32 + (lane & 15)] = (__bf16)val;
    outp[row * 32 + 16 + (lane & 15)] = (__bf16)0.f;  // zero pad K 16->32
  }
}

// ---------------- fused attention: S=qq.kk^T (MFMA), P=exp(S^2) in LDS,
//                  attended = (P @ v) / rowsum ----------------
#define PSTR 136  // P LDS row stride in bf16 (16B-aligned, bank-spread)
__global__ __launch_bounds__(256) void fused_attn(
    const __bf16* __restrict__ qq32, const __bf16* __restrict__ kk32,
    const __bf16* __restrict__ v_t, __bf16* __restrict__ attn) {
  __shared__ __bf16 Plds[128 * PSTR];
  __shared__ __bf16 Vlds[128 * 128];
  __shared__ float rsum2[128 * 2];
  const int tid = threadIdx.x;
  const int lane = tid & 63;
  const int w = tid >> 6;
  const int wm = w >> 1, wn = w & 1;
  const int l15 = lane & 15, quad = lane >> 4;
  const int b = blockIdx.z;
  const long qbase = (long)blockIdx.y * 128;
  const long hbase = (long)blockIdx.x * 128;

  // qq A-frags: constant across the k-loop, straight from global to VGPR
  bf16x8 aq[4];
  {
    const __bf16* qqp =
        qq32 + ((long)b * SEQ + qbase + wm * 64 + l15) * 32 + quad * 8;
#pragma unroll
    for (int i = 0; i < 4; ++i) aq[i] = *(const bf16x8*)(qqp + (long)i * 16 * 32);
  }
  const __bf16* kkb = kk32 + (long)b * SEQ * 32;
  const __bf16* vtb = v_t + (long)b * H * SEQ + hbase * SEQ;

  // v_t chunk staging (global_load_lds): thread -> (row=tid>>4, seg=tid&15)
  const __bf16* vg = vtb + (long)(tid >> 4) * SEQ + (tid & 15) * 8;
  __bf16* vl = &Vlds[(tid >> 4) * 128 + (tid & 15) * 8];

  f32x4 acc[4][4];
#pragma unroll
  for (int i = 0; i < 4; ++i)
#pragma unroll
    for (int j = 0; j < 4; ++j) {
      acc[i][j][0] = 0.f; acc[i][j][1] = 0.f; acc[i][j][2] = 0.f; acc[i][j][3] = 0.f;
    }
  float rs[4][4];
#pragma unroll
  for (int i = 0; i < 4; ++i)
#pragma unroll
    for (int r = 0; r < 4; ++r) rs[i][r] = 0.f;

  for (int k0 = 0; k0 < SEQ; k0 += 128) {
    // stage v_t[hbase:+128][k0:+128] -> Vlds (async; drained at the barrier)
#pragma unroll
    for (int j = 0; j < 8; ++j)
      async_g2l_16(vg + (long)k0 + (long)j * 16 * SEQ, vl + j * 16 * 128);

    // kk B-frags for this chunk (global -> VGPR, L2-hot)
    bf16x8 bk[4];
    {
      const __bf16* kkp = kkb + (long)(k0 + wn * 64 + l15) * 32 + quad * 8;
#pragma unroll
      for (int n = 0; n < 4; ++n)
        bk[n] = *(const bf16x8*)(kkp + (long)n * 16 * 32);
    }
    // S = qq @ kk^T, then P = exp(S^2) -> LDS (A-operand layout)
#pragma unroll
    for (int i = 0; i < 4; ++i) {
#pragma unroll
      for (int n = 0; n < 4; ++n) {
        f32x4 s;
        s[0] = 0.f; s[1] = 0.f; s[2] = 0.f; s[3] = 0.f;
        s = __builtin_amdgcn_mfma_f32_16x16x32_bf16(aq[i], bk[n], s, 0, 0, 0);
        const int colL = wn * 64 + n * 16 + l15;
#pragma unroll
        for (int r = 0; r < 4; ++r) {
          float wgt = __expf(s[r] * s[r]);
          rs[i][r] += wgt;
          Plds[(wm * 64 + i * 16 + quad * 4 + r) * PSTR + colL] = (__bf16)wgt;
        }
      }
    }
    __syncthreads();
    // PV: acc += P[128q x 128k] @ v[128k x 128h]
#pragma unroll
    for (int ks = 0; ks < 4; ++ks) {
      bf16x8 ap[4], bv[4];
#pragma unroll
      for (int i = 0; i < 4; ++i)
        ap[i] = *(const bf16x8*)&Plds[(wm * 64 + i * 16 + l15) * PSTR + ks * 32 +
                                      quad * 8];
#pragma unroll
      for (int j = 0; j < 4; ++j)
        bv[j] = *(const bf16x8*)&Vlds[(wn * 64 + j * 16 + l15) * 128 + ks * 32 +
                                      quad * 8];
#pragma unroll
      for (int i = 0; i < 4; ++i)
#pragma unroll
        for (int j = 0; j < 4; ++j)
          acc[i][j] =
              __builtin_amdgcn_mfma_f32_16x16x32_bf16(ap[i], bv[j], acc[i][j], 0, 0, 0);
    }
    __syncthreads();
  }

  // rowsum: reduce across the 16 column-lanes, combine the two wn waves via LDS
#pragma unroll
  for (int i = 0; i < 4; ++i)
#pragma unroll
    for (int r = 0; r < 4; ++r) {
      float vsum = rs[i][r];
      vsum += __shfl_xor(vsum, 1);
      vsum += __shfl_xor(vsum, 2);
      vsum += __shfl_xor(vsum, 4);
      vsum += __shfl_xor(vsum, 8);
      rs[i][r] = vsum;
    }
  if (l15 == 0) {
#pragma unroll
    for (int i = 0; i < 4; ++i)
#pragma unroll
      for (int r = 0; r < 4; ++r)
        rsum2[(wm * 64 + i * 16 + quad * 4 + r) * 2 + wn] = rs[i][r];
  }
  __syncthreads();

  float rinv[4][4];
#pragma unroll
  for (int i = 0; i < 4; ++i)
#pragma unroll
    for (int r = 0; r < 4; ++r) {
      int row = wm * 64 + i * 16 + quad * 4 + r;
      rinv[i][r] = 1.0f / (rsum2[row * 2] + rsum2[row * 2 + 1]);
    }

  __bf16* ob = attn + ((long)b * SEQ + qbase) * H + hbase;
#pragma unroll
  for (int i = 0; i < 4; ++i)
#pragma unroll
    for (int j = 0; j < 4; ++j) {
      const int colL = wn * 64 + j * 16 + l15;
#pragma unroll
      for (int r = 0; r < 4; ++r) {
        const int rowL = wm * 64 + i * 16 + quad * 4 + r;
        ob[(long)rowL * H + colL] = (__bf16)(acc[i][j][r] * rinv[i][r]);
      }
    }
}

// ---------------- m97-style GEMM: C = A[MxK] @ Bt[NxK]^T (+bias) ----------------
template <int OUTF32, int HASBIAS>
__global__ __launch_bounds__(256) void gemm_bt(
    const __bf16* __restrict__ A, const __bf16* __restrict__ Bt,
    void* __restrict__ Cout, const float* __restrict__ bias, int M, int N, int K) {
  __shared__ __bf16 Alds[128 * 64];
  __shared__ __bf16 Blds[128 * 64];
  const int tid = threadIdx.x;
  const int lane = tid & 63;
  const int w = tid >> 6;
  const int wm = w >> 1, wn = w & 1;
  const long rowBase = (long)blockIdx.y * 128;
  const long colBase = (long)blockIdx.x * 128;

  const int srow = lane >> 3;
  const int skk = (lane & 7) * 8;

  const __bf16* ag[4];
  const __bf16* bg[4];
  __bf16* as_[4];
  __bf16* bs_[4];
#pragma unroll
  for (int j = 0; j < 4; ++j) {
    int r = j * 32 + w * 8;
    ag[j] = A + (rowBase + r + srow) * (long)K + skk;
    bg[j] = Bt + (colBase + r + srow) * (long)K + skk;
    as_[j] = &Alds[r * 64];
    bs_[j] = &Blds[r * 64];
  }

  f32x4 acc[4][4];
#pragma unroll
  for (int i = 0; i < 4; ++i)
#pragma unroll
    for (int j = 0; j < 4; ++j) {
      acc[i][j][0] = 0.f; acc[i][j][1] = 0.f; acc[i][j][2] = 0.f; acc[i][j][3] = 0.f;
    }

  const int afrag0 = (wm * 64 + (lane & 15)) * 64 + ((lane >> 4) * 8);
  const int bfrag0 = (wn * 64 + (lane & 15)) * 64 + ((lane >> 4) * 8);

  for (int k0 = 0; k0 < K; k0 += 64) {
#pragma unroll
    for (int j = 0; j < 4; ++j) {
      async_g2l_16(ag[j], as_[j]);
      async_g2l_16(bg[j], bs_[j]);
      ag[j] += 64;
      bg[j] += 64;
    }
    __syncthreads();
#pragma unroll
    for (int s = 0; s < 2; ++s) {
      bf16x8 af[4], bfv[4];
#pragma unroll
      for (int i = 0; i < 4; ++i) {
        af[i] = *(const bf16x8*)&Alds[afrag0 + i * 16 * 64 + s * 32];
        bfv[i] = *(const bf16x8*)&Blds[bfrag0 + i * 16 * 64 + s * 32];
      }
#pragma unroll
      for (int i = 0; i < 4; ++i)
#pragma unroll
        for (int j = 0; j < 4; ++j)
          acc[i][j] =
              __builtin_amdgcn_mfma_f32_16x16x32_bf16(af[i], bfv[j], acc[i][j], 0, 0, 0);
    }
    __syncthreads();
  }

  const long crow0 = rowBase + wm * 64 + ((lane >> 4) * 4);
  const long ccol0 = colBase + wn * 64 + (lane & 15);
#pragma unroll
  for (int i = 0; i < 4; ++i) {
#pragma unroll
    for (int j = 0; j < 4; ++j) {
      long col = ccol0 + j * 16;
      float bb = HASBIAS ? bias[col] : 0.f;
#pragma unroll
      for (int r = 0; r < 4; ++r) {
        long row = crow0 + i * 16 + r;
        float val = acc[i][j][r] + bb;
        if (OUTF32)
          ((float*)Cout)[row * N + col] = val;
        else
          ((__bf16*)Cout)[row * N + col] = (__bf16)val;
      }
    }
  }
}

extern "C" void kernel_launch(void* const* d_in, const int* in_sizes, int n_in,
                              void* d_out, int out_size, void* d_ws, size_t ws_size,
                              hipStream_t stream) {
  const float* x = (const float*)d_in[0];
  const float* Wq = (const float*)d_in[1];
  const float* bq = (const float*)d_in[2];
  const float* Wk = (const float*)d_in[3];
  const float* bk = (const float*)d_in[4];
  const float* Wv = (const float*)d_in[5];
  const float* bv = (const float*)d_in[6];
  const float* We = (const float*)d_in[7];
  const float* be = (const float*)d_in[8];
  const float* Wo = (const float*)d_in[9];
  const float* bo = (const float*)d_in[10];
  float* out = (float*)d_out;

  char* ws = (char*)d_ws;
  size_t o = 0;
  auto alloc = [&](size_t n) {
    size_t r = o;
    o += (n + 255) & ~(size_t)255;
    return r;
  };
  __bf16* xbf = (__bf16*)(ws + alloc((size_t)MROWS * H * 2));   // x hi
  __bf16* v = (__bf16*)(ws + alloc((size_t)MROWS * H * 2));
  __bf16* attn = (__bf16*)(ws + alloc((size_t)MROWS * H * 2));
  __bf16* Wvt = (__bf16*)(ws + alloc((size_t)H * H * 2));
  __bf16* Wot = (__bf16*)(ws + alloc((size_t)H * H * 2));
  __bf16* Cth = (__bf16*)(ws + alloc((size_t)32 * H * 2));
  __bf16* Ctl = (__bf16*)(ws + alloc((size_t)32 * H * 2));
  float* dvec = (float*)(ws + alloc(32 * 4));
  __bf16* qq32 = (__bf16*)(ws + alloc((size_t)MROWS * 32 * 2));
  __bf16* kk32 = (__bf16*)(ws + alloc((size_t)MROWS * 32 * 2));
  // Aliases (stream-ordered lifetime separation):
  __bf16* xlo = attn;  // x lo part: dead before attn is written (fused_attn)
  __bf16* v_t = xbf;   // v^T: xbf dead after the v GEMM
  if (ws_size < o) return;

  // 1) x -> bf16 hi/lo split
  cvt_split<<<MROWS * H / 1024, 256, 0, stream>>>(x, xbf, xlo, MROWS * H);
  // 2) Wv^T, Wo^T as bf16
  transpose_cvt_f32_bf16<<<dim3(32, 32), 256, 0, stream>>>(Wv, Wvt, H, H);
  transpose_cvt_f32_bf16<<<dim3(32, 32), 256, 0, stream>>>(Wo, Wot, H, H);
  // 3) collapsed embed matrices (bf16 hi/lo, Bt layout) + bias fold
  k2_cqk<<<512, 256, 0, stream>>>(Wq, Wk, We, Cth, Ctl);
  k2b_dvec<<<1, 64, 0, stream>>>(bq, bk, We, be, dvec);
  // 4) unit-norm quantum embeds via MFMA -> bf16 [S][32] zero-padded
  k3_embed_mfma<<<MROWS / 32, 256, 0, stream>>>(xbf, xlo, Cth, Ctl, dvec, qq32, kk32);
  // 5) v = x@Wv + bv  (bf16 MFMA)
  gemm_bt<0, 1><<<dim3(8, 64), 256, 0, stream>>>(xbf, Wvt, v, bv, MROWS, H, H);
  // 6) v^T per batch
  transpose_bf16_batched<<<dim3(32, 64, BATCH), 256, 0, stream>>>(
      v, v_t, SEQ, H, (long)SEQ * H, (long)H * SEQ);
  // 7) fused: S -> exp(S^2) -> P@v/rowsum  (bf16 out)
  fused_attn<<<dim3(8, 16, BATCH), 256, 0, stream>>>(qq32, kk32, v_t, attn);
  // 8) out = attended @ Wo + bo  (fp32 out)
  gemm_bt<1, 1><<<dim3(8, 64), 256, 0, stream>>>(attn, Wot, out, bo, MROWS, H, H);
}

// Round 4
// 273.654 us; speedup vs baseline: 1.1754x; 1.1754x over previous
//
#include <hip/hip_runtime.h>

#define H 1024
#define QD 16
#define BATCH 4
#define SEQ 2048
#define MROWS 8192  // BATCH*SEQ

typedef __bf16 bf16x8 __attribute__((ext_vector_type(8)));
typedef __bf16 bf16x4 __attribute__((ext_vector_type(4)));
typedef float f32x4 __attribute__((ext_vector_type(4)));

__device__ __forceinline__ void async_g2l_16(const void* g, void* l) {
  __builtin_amdgcn_global_load_lds(
      (const __attribute__((address_space(1))) unsigned int*)g,
      (__attribute__((address_space(3))) unsigned int*)l, 16, 0, 0);
}

// ---------------- fp32 -> bf16 hi/lo split (x) ----------------
__global__ __launch_bounds__(256) void cvt_split(const float* __restrict__ src,
                                                 __bf16* __restrict__ hi,
                                                 __bf16* __restrict__ lo, int n) {
  int i = (blockIdx.x * 256 + threadIdx.x) * 4;
  if (i < n) {
    float4 f = *(const float4*)(src + i);
    bf16x4 h, l;
    h[0] = (__bf16)f.x; l[0] = (__bf16)(f.x - (float)h[0]);
    h[1] = (__bf16)f.y; l[1] = (__bf16)(f.y - (float)h[1]);
    h[2] = (__bf16)f.z; l[2] = (__bf16)(f.z - (float)h[2]);
    h[3] = (__bf16)f.w; l[3] = (__bf16)(f.w - (float)h[3]);
    *(bf16x4*)(hi + i) = h;
    *(bf16x4*)(lo + i) = l;
  }
}

// ---------------- fp32 [R][C] -> bf16 transposed [C][R] ----------------
__global__ __launch_bounds__(256) void transpose_cvt_f32_bf16(
    const float* __restrict__ src, __bf16* __restrict__ dst, int R, int C) {
  __shared__ float t[32][33];
  const int rb = blockIdx.y * 32, cb = blockIdx.x * 32;
  const int c = threadIdx.x & 31;
  const int r0 = threadIdx.x >> 5;
#pragma unroll
  for (int rr = r0; rr < 32; rr += 8)
    t[rr][c] = src[(long)(rb + rr) * C + cb + c];
  __syncthreads();
#pragma unroll
  for (int rr = r0; rr < 32; rr += 8)
    dst[(long)(cb + rr) * R + rb + c] = (__bf16)t[c][rr];
}

// ---------------- bf16 [R][C] -> bf16 transposed [C][R], batched ----------------
__global__ __launch_bounds__(256) void transpose_bf16_batched(
    const __bf16* __restrict__ src, __bf16* __restrict__ dst, int R, int C,
    long sS, long sD) {
  __shared__ __bf16 t[32][33];
  const __bf16* s = src + (long)blockIdx.z * sS;
  __bf16* d = dst + (long)blockIdx.z * sD;
  const int rb = blockIdx.y * 32, cb = blockIdx.x * 32;
  const int c = threadIdx.x & 31;
  const int r0 = threadIdx.x >> 5;
#pragma unroll
  for (int rr = r0; rr < 32; rr += 8)
    t[rr][c] = s[(long)(rb + rr) * C + cb + c];
  __syncthreads();
#pragma unroll
  for (int rr = r0; rr < 32; rr += 8)
    d[(long)(cb + rr) * R + rb + c] = t[c][rr];
}

// ---------------- CqkT (Bt layout [32][1024]) in bf16 hi/lo ----------------
__global__ __launch_bounds__(256) void k2_cqk(const float* __restrict__ Wq,
                                              const float* __restrict__ Wk,
                                              const float* __restrict__ We,
                                              __bf16* __restrict__ Cth,
                                              __bf16* __restrict__ Ctl) {
  const int gw = blockIdx.x * 4 + (threadIdx.x >> 6);  // 0..2047
  const int lane = threadIdx.x & 63;
  const int mat = gw & 1, k = gw >> 1;
  const float* Wrow = (mat ? Wk : Wq) + (long)k * H;
  const int col = lane & 15, q4 = lane >> 4;
  float acc = 0.f;
  for (int n0 = 0; n0 < 256; ++n0) {
    int n = q4 * 256 + n0;
    acc += Wrow[n] * We[n * QD + col];
  }
  acc += __shfl_xor(acc, 16);
  acc += __shfl_xor(acc, 32);
  if (lane < 16) {
    __bf16 hi = (__bf16)acc;
    __bf16 lo = (__bf16)(acc - (float)hi);
    long idx = (long)(mat * 16 + col) * H + k;
    Cth[idx] = hi;
    Ctl[idx] = lo;
  }
}

// ---------------- dvec[j] = (bq|bk)@We + be ----------------
__global__ void k2b_dvec(const float* __restrict__ bq, const float* __restrict__ bk,
                         const float* __restrict__ We, const float* __restrict__ be,
                         float* __restrict__ dvec) {
  int j = threadIdx.x;
  if (j < 32) {
    int mat = j >> 4, col = j & 15;
    const float* b = mat ? bk : bq;
    float acc = be[col];
    for (int n = 0; n < H; ++n) acc += b[n] * We[n * QD + col];
    dvec[j] = acc;
  }
}

// ---------------- embed via MFMA (hi/lo split), fused normalize ----------------
// Outputs bf16 qq/kk in [S][32] layout with zero-padded upper K half.
// LDS staging uses XOR-swizzled segments for bank-uniform frag reads.
__global__ __launch_bounds__(256) void k3_embed_mfma(
    const __bf16* __restrict__ xh, const __bf16* __restrict__ xl,
    const __bf16* __restrict__ Cth, const __bf16* __restrict__ Ctl,
    const float* __restrict__ dvec, __bf16* __restrict__ qq32,
    __bf16* __restrict__ kk32) {
  __shared__ __bf16 Ah[32 * 64];
  __shared__ __bf16 Al[32 * 64];
  __shared__ __bf16 Bh[32 * 64];
  __shared__ __bf16 Bl[32 * 64];
  const int tid = threadIdx.x;
  const int lane = tid & 63;
  const int w = tid >> 6;
  const int rowhalf = w >> 1;  // 0/1 -> rows 0-15 / 16-31
  const int ntile = w & 1;     // 0 -> qq, 1 -> kk
  const int l15 = lane & 15, quad = lane >> 4;
  const long rowBase = (long)blockIdx.x * 32;

  const int srow = tid >> 3;                     // 0..31 (LDS row)
  const int segsw = ((tid & 7) ^ (srow & 7)) * 8;  // swizzled global k-seg
  const __bf16* agh = xh + (rowBase + srow) * H + segsw;
  const __bf16* agl = xl + (rowBase + srow) * H + segsw;
  const __bf16* bgh = Cth + (long)srow * H + segsw;
  const __bf16* bgl = Ctl + (long)srow * H + segsw;
  __bf16* lah = &Ah[srow * 64 + (tid & 7) * 8];
  __bf16* lal = &Al[srow * 64 + (tid & 7) * 8];
  __bf16* lbh = &Bh[srow * 64 + (tid & 7) * 8];
  __bf16* lbl = &Bl[srow * 64 + (tid & 7) * 8];

  f32x4 acc;
  acc[0] = 0.f; acc[1] = 0.f; acc[2] = 0.f; acc[3] = 0.f;
  const int arow = (rowhalf * 16 + l15) * 64;
  const int brow = (ntile * 16 + l15) * 64;
  const int h7 = l15 & 7;

  for (int k0 = 0; k0 < H; k0 += 64) {
    async_g2l_16(agh + k0, lah);
    async_g2l_16(agl + k0, lal);
    async_g2l_16(bgh + k0, lbh);
    async_g2l_16(bgl + k0, lbl);
    __syncthreads();
#pragma unroll
    for (int s = 0; s < 2; ++s) {
      const int slot = ((s * 4 + quad) ^ h7) * 8;
      bf16x8 fah = *(const bf16x8*)&Ah[arow + slot];
      bf16x8 fal = *(const bf16x8*)&Al[arow + slot];
      bf16x8 fbh = *(const bf16x8*)&Bh[brow + slot];
      bf16x8 fbl = *(const bf16x8*)&Bl[brow + slot];
      acc = __builtin_amdgcn_mfma_f32_16x16x32_bf16(fah, fbh, acc, 0, 0, 0);
      acc = __builtin_amdgcn_mfma_f32_16x16x32_bf16(fal, fbh, acc, 0, 0, 0);
      acc = __builtin_amdgcn_mfma_f32_16x16x32_bf16(fah, fbl, acc, 0, 0, 0);
    }
    __syncthreads();
  }

  const float dv = dvec[ntile * 16 + l15];
  __bf16* outp = ntile ? kk32 : qq32;
#pragma unroll
  for (int r = 0; r < 4; ++r) {
    float z = acc[r] + dv;
    float s2 = z * z;
    s2 += __shfl_xor(s2, 1);
    s2 += __shfl_xor(s2, 2);
    s2 += __shfl_xor(s2, 4);
    s2 += __shfl_xor(s2, 8);
    float val = z * rsqrtf(s2 + 1e-8f);
    long row = rowBase + rowhalf * 16 + quad * 4 + r;
    outp[row * 32 + l15] = (__bf16)val;
    outp[row * 32 + 16 + l15] = (__bf16)0.f;  // zero pad K 16->32
  }
}

// ---------------- fused attention ----------------
// S^T = kk@qq^T per chunk (C-layout lane holds 4 consecutive k of one q row
// -> single ds_write_b64 of exp(S^2)). PV from LDS with XOR-swizzled Vlds.
#define PSTR 136  // Plds row stride in bf16 (68 dwords == 4 mod 32 -> uniform banks)
__global__ __launch_bounds__(256) void fused_attn(
    const __bf16* __restrict__ qq32, const __bf16* __restrict__ kk32,
    const __bf16* __restrict__ v_t, __bf16* __restrict__ attn) {
  __shared__ __bf16 Plds[128 * PSTR];
  __shared__ __bf16 Vlds[128 * 128];
  __shared__ float rsum2[128 * 2];
  const int tid = threadIdx.x;
  const int lane = tid & 63;
  const int w = tid >> 6;
  const int wa = w >> 1;  // S: k-tile half | PV: q-row half
  const int wb = w & 1;   // S: q-tile half | PV: h-col half
  const int l15 = lane & 15, quad = lane >> 4;
  const int b = blockIdx.z;
  const long qbase = (long)blockIdx.y * 128;
  const long hbase = (long)blockIdx.x * 128;

  // qq B-frags: constant across the k-loop
  bf16x8 bq[4];
  {
    const __bf16* qqp =
        qq32 + ((long)b * SEQ + qbase + wb * 64 + l15) * 32 + quad * 8;
#pragma unroll
    for (int n = 0; n < 4; ++n) bq[n] = *(const bf16x8*)(qqp + (long)n * 16 * 32);
  }
  const __bf16* kkb = kk32 + ((long)b * SEQ + wa * 64 + l15) * 32 + quad * 8;

  // V staging: XOR-swizzled global segment (g2l dest is lane-ordered)
  const int vrow = tid >> 4;                      // 0..15
  const int vsegsw = ((tid & 15) ^ (vrow & 15)) * 8;
  const __bf16* vg = v_t + (long)b * H * SEQ + (hbase + vrow) * SEQ + vsegsw;
  __bf16* vl = &Vlds[vrow * 128 + (tid & 15) * 8];

  f32x4 acc[4][4];
#pragma unroll
  for (int i = 0; i < 4; ++i)
#pragma unroll
    for (int j = 0; j < 4; ++j) {
      acc[i][j][0] = 0.f; acc[i][j][1] = 0.f; acc[i][j][2] = 0.f; acc[i][j][3] = 0.f;
    }
  float rsPart[4] = {0.f, 0.f, 0.f, 0.f};

  // preload kk A-frags for chunk 0
  bf16x8 ak[4];
#pragma unroll
  for (int i = 0; i < 4; ++i) ak[i] = *(const bf16x8*)(kkb + (long)(i * 16) * 32);

  for (int k0 = 0; k0 < SEQ; k0 += 128) {
    // stage v_t[hbase:+128][k0:+128] -> Vlds (drained at the barrier)
#pragma unroll
    for (int j = 0; j < 8; ++j)
      async_g2l_16(vg + (long)k0 + (long)(j * 16) * SEQ, vl + j * 16 * 128);

    // S^T phase: lane holds S^T[k=wa*64+i*16+quad*4+r][q=wb*64+n*16+l15]
#pragma unroll
    for (int i = 0; i < 4; ++i) {
#pragma unroll
      for (int n = 0; n < 4; ++n) {
        f32x4 s;
        s[0] = 0.f; s[1] = 0.f; s[2] = 0.f; s[3] = 0.f;
        s = __builtin_amdgcn_mfma_f32_16x16x32_bf16(ak[i], bq[n], s, 0, 0, 0);
        bf16x4 pw;
        float part = 0.f;
#pragma unroll
        for (int r = 0; r < 4; ++r) {
          float wgt = __expf(s[r] * s[r]);
          part += wgt;
          pw[r] = (__bf16)wgt;
        }
        rsPart[n] += part;
        *(bf16x4*)&Plds[(wb * 64 + n * 16 + l15) * PSTR + wa * 64 + i * 16 +
                        quad * 4] = pw;
      }
    }
    // prefetch next chunk's kk frags (in flight across the PV phase)
    if (k0 + 128 < SEQ) {
#pragma unroll
      for (int i = 0; i < 4; ++i)
        ak[i] = *(const bf16x8*)(kkb + (long)(k0 + 128 + i * 16) * 32);
    }
    __syncthreads();
    // PV: acc += P[128q x 128k] @ v^T[128h x 128k]^T
#pragma unroll
    for (int ks = 0; ks < 4; ++ks) {
      bf16x8 ap[4], bv[4];
#pragma unroll
      for (int i = 0; i < 4; ++i)
        ap[i] = *(const bf16x8*)&Plds[(wa * 64 + i * 16 + l15) * PSTR + ks * 32 +
                                      quad * 8];
#pragma unroll
      for (int j = 0; j < 4; ++j) {
        const int vr = wb * 64 + j * 16 + l15;
        const int slot = ((ks * 4 + quad) ^ l15) * 8;
        bv[j] = *(const bf16x8*)&Vlds[vr * 128 + slot];
      }
#pragma unroll
      for (int i = 0; i < 4; ++i)
#pragma unroll
        for (int j = 0; j < 4; ++j)
          acc[i][j] =
              __builtin_amdgcn_mfma_f32_16x16x32_bf16(ap[i], bv[j], acc[i][j], 0, 0, 0);
    }
    __syncthreads();
  }

  // rowsum: rsPart[n] covers this lane's quad over this wave's k-half; reduce
  // over quad lanes, then combine the two wa halves via LDS.
#pragma unroll
  for (int n = 0; n < 4; ++n) {
    float vs = rsPart[n];
    vs += __shfl_xor(vs, 16);
    vs += __shfl_xor(vs, 32);
    if (lane < 16)
      rsum2[(wb * 64 + n * 16 + l15) * 2 + wa] = vs;
  }
  __syncthreads();

  float rinv[4][4];
#pragma unroll
  for (int i = 0; i < 4; ++i)
#pragma unroll
    for (int r = 0; r < 4; ++r) {
      int row = wa * 64 + i * 16 + quad * 4 + r;
      rinv[i][r] = 1.0f / (rsum2[row * 2] + rsum2[row * 2 + 1]);
    }

  __bf16* ob = attn + ((long)b * SEQ + qbase) * H + hbase;
#pragma unroll
  for (int i = 0; i < 4; ++i)
#pragma unroll
    for (int j = 0; j < 4; ++j) {
      const int colL = wb * 64 + j * 16 + l15;
#pragma unroll
      for (int r = 0; r < 4; ++r) {
        const int rowL = wa * 64 + i * 16 + quad * 4 + r;
        ob[(long)rowL * H + colL] = (__bf16)(acc[i][j][r] * rinv[i][r]);
      }
    }
}

// ---------------- m97-style GEMM + XOR-swizzled LDS: C = A @ Bt^T (+bias) ----------------
template <int OUTF32, int HASBIAS>
__global__ __launch_bounds__(256) void gemm_bt(
    const __bf16* __restrict__ A, const __bf16* __restrict__ Bt,
    void* __restrict__ Cout, const float* __restrict__ bias, int M, int N, int K) {
  __shared__ __bf16 Alds[128 * 64];
  __shared__ __bf16 Blds[128 * 64];
  const int tid = threadIdx.x;
  const int lane = tid & 63;
  const int w = tid >> 6;
  const int wm = w >> 1, wn = w & 1;
  const int l15 = lane & 15, quad = lane >> 4;
  const long rowBase = (long)blockIdx.y * 128;
  const long colBase = (long)blockIdx.x * 128;

  const int srow = lane >> 3;                      // 0..7
  const int segsw = ((lane & 7) ^ srow) * 8;       // swizzled global k-seg

  const __bf16* ag[4];
  const __bf16* bg[4];
  __bf16* as_[4];
  __bf16* bs_[4];
#pragma unroll
  for (int j = 0; j < 4; ++j) {
    int r = j * 32 + w * 8;
    ag[j] = A + (rowBase + r + srow) * (long)K + segsw;
    bg[j] = Bt + (colBase + r + srow) * (long)K + segsw;
    as_[j] = &Alds[r * 64 + (lane & 7) * 8];
    bs_[j] = &Blds[r * 64 + (lane & 7) * 8];
  }

  f32x4 acc[4][4];
#pragma unroll
  for (int i = 0; i < 4; ++i)
#pragma unroll
    for (int j = 0; j < 4; ++j) {
      acc[i][j][0] = 0.f; acc[i][j][1] = 0.f; acc[i][j][2] = 0.f; acc[i][j][3] = 0.f;
    }

  const int h7 = l15 & 7;

  for (int k0 = 0; k0 < K; k0 += 64) {
#pragma unroll
    for (int j = 0; j < 4; ++j) {
      async_g2l_16(ag[j], as_[j]);
      async_g2l_16(bg[j], bs_[j]);
      ag[j] += 64;
      bg[j] += 64;
    }
    __syncthreads();
#pragma unroll
    for (int s = 0; s < 2; ++s) {
      const int slot = ((s * 4 + quad) ^ h7) * 8;
      bf16x8 af[4], bfv[4];
#pragma unroll
      for (int i = 0; i < 4; ++i) {
        af[i] = *(const bf16x8*)&Alds[(wm * 64 + i * 16 + l15) * 64 + slot];
        bfv[i] = *(const bf16x8*)&Blds[(wn * 64 + i * 16 + l15) * 64 + slot];
      }
#pragma unroll
      for (int i = 0; i < 4; ++i)
#pragma unroll
        for (int j = 0; j < 4; ++j)
          acc[i][j] =
              __builtin_amdgcn_mfma_f32_16x16x32_bf16(af[i], bfv[j], acc[i][j], 0, 0, 0);
    }
    __syncthreads();
  }

  const long crow0 = rowBase + wm * 64 + quad * 4;
  const long ccol0 = colBase + wn * 64 + l15;
#pragma unroll
  for (int i = 0; i < 4; ++i) {
#pragma unroll
    for (int j = 0; j < 4; ++j) {
      long col = ccol0 + j * 16;
      float bb = HASBIAS ? bias[col] : 0.f;
#pragma unroll
      for (int r = 0; r < 4; ++r) {
        long row = crow0 + i * 16 + r;
        float val = acc[i][j][r] + bb;
        if (OUTF32)
          ((float*)Cout)[row * N + col] = val;
        else
          ((__bf16*)Cout)[row * N + col] = (__bf16)val;
      }
    }
  }
}

extern "C" void kernel_launch(void* const* d_in, const int* in_sizes, int n_in,
                              void* d_out, int out_size, void* d_ws, size_t ws_size,
                              hipStream_t stream) {
  const float* x = (const float*)d_in[0];
  const float* Wq = (const float*)d_in[1];
  const float* bq = (const float*)d_in[2];
  const float* Wk = (const float*)d_in[3];
  const float* bk = (const float*)d_in[4];
  const float* Wv = (const float*)d_in[5];
  const float* bv = (const float*)d_in[6];
  const float* We = (const float*)d_in[7];
  const float* be = (const float*)d_in[8];
  const float* Wo = (const float*)d_in[9];
  const float* bo = (const float*)d_in[10];
  float* out = (float*)d_out;

  char* ws = (char*)d_ws;
  size_t o = 0;
  auto alloc = [&](size_t n) {
    size_t r = o;
    o += (n + 255) & ~(size_t)255;
    return r;
  };
  __bf16* xbf = (__bf16*)(ws + alloc((size_t)MROWS * H * 2));   // x hi
  __bf16* v = (__bf16*)(ws + alloc((size_t)MROWS * H * 2));
  __bf16* attn = (__bf16*)(ws + alloc((size_t)MROWS * H * 2));
  __bf16* Wvt = (__bf16*)(ws + alloc((size_t)H * H * 2));
  __bf16* Wot = (__bf16*)(ws + alloc((size_t)H * H * 2));
  __bf16* Cth = (__bf16*)(ws + alloc((size_t)32 * H * 2));
  __bf16* Ctl = (__bf16*)(ws + alloc((size_t)32 * H * 2));
  float* dvec = (float*)(ws + alloc(32 * 4));
  __bf16* qq32 = (__bf16*)(ws + alloc((size_t)MROWS * 32 * 2));
  __bf16* kk32 = (__bf16*)(ws + alloc((size_t)MROWS * 32 * 2));
  // Aliases (stream-ordered lifetime separation):
  __bf16* xlo = attn;  // x lo part: dead before attn is written (fused_attn)
  __bf16* v_t = xbf;   // v^T: xbf dead after the v GEMM
  if (ws_size < o) return;

  // 1) x -> bf16 hi/lo split
  cvt_split<<<MROWS * H / 1024, 256, 0, stream>>>(x, xbf, xlo, MROWS * H);
  // 2) Wv^T, Wo^T as bf16
  transpose_cvt_f32_bf16<<<dim3(32, 32), 256, 0, stream>>>(Wv, Wvt, H, H);
  transpose_cvt_f32_bf16<<<dim3(32, 32), 256, 0, stream>>>(Wo, Wot, H, H);
  // 3) collapsed embed matrices (bf16 hi/lo, Bt layout) + bias fold
  k2_cqk<<<512, 256, 0, stream>>>(Wq, Wk, We, Cth, Ctl);
  k2b_dvec<<<1, 64, 0, stream>>>(bq, bk, We, be, dvec);
  // 4) unit-norm quantum embeds via MFMA -> bf16 [S][32] zero-padded
  k3_embed_mfma<<<MROWS / 32, 256, 0, stream>>>(xbf, xlo, Cth, Ctl, dvec, qq32, kk32);
  // 5) v = x@Wv + bv  (bf16 MFMA)
  gemm_bt<0, 1><<<dim3(8, 64), 256, 0, stream>>>(xbf, Wvt, v, bv, MROWS, H, H);
  // 6) v^T per batch
  transpose_bf16_batched<<<dim3(32, 64, BATCH), 256, 0, stream>>>(
      v, v_t, SEQ, H, (long)SEQ * H, (long)H * SEQ);
  // 7) fused: S^T -> exp(S^2) -> P@v/rowsum  (bf16 out)
  fused_attn<<<dim3(8, 16, BATCH), 256, 0, stream>>>(qq32, kk32, v_t, attn);
  // 8) out = attended @ Wo + bo  (fp32 out)
  gemm_bt<1, 1><<<dim3(8, 64), 256, 0, stream>>>(attn, Wot, out, bo, MROWS, H, H);
}

// Round 5
// 264.542 us; speedup vs baseline: 1.2159x; 1.0344x over previous
//
#include <hip/hip_runtime.h>

#define H 1024
#define QD 16
#define BATCH 4
#define SEQ 2048
#define MROWS 8192  // BATCH*SEQ

typedef __bf16 bf16x8 __attribute__((ext_vector_type(8)));
typedef __bf16 bf16x4 __attribute__((ext_vector_type(4)));
typedef float f32x4 __attribute__((ext_vector_type(4)));

__device__ __forceinline__ void async_g2l_16(const void* g, void* l) {
  __builtin_amdgcn_global_load_lds(
      (const __attribute__((address_space(1))) unsigned int*)g,
      (__attribute__((address_space(3))) unsigned int*)l, 16, 0, 0);
}

// ---------------- fp32 -> bf16 hi/lo split (x) ----------------
__global__ __launch_bounds__(256) void cvt_split(const float* __restrict__ src,
                                                 __bf16* __restrict__ hi,
                                                 __bf16* __restrict__ lo, int n) {
  int i = (blockIdx.x * 256 + threadIdx.x) * 4;
  if (i < n) {
    float4 f = *(const float4*)(src + i);
    bf16x4 h, l;
    h[0] = (__bf16)f.x; l[0] = (__bf16)(f.x - (float)h[0]);
    h[1] = (__bf16)f.y; l[1] = (__bf16)(f.y - (float)h[1]);
    h[2] = (__bf16)f.z; l[2] = (__bf16)(f.z - (float)h[2]);
    h[3] = (__bf16)f.w; l[3] = (__bf16)(f.w - (float)h[3]);
    *(bf16x4*)(hi + i) = h;
    *(bf16x4*)(lo + i) = l;
  }
}

// ---------------- fp32 [R][C] -> bf16 transposed [C][R] ----------------
__global__ __launch_bounds__(256) void transpose_cvt_f32_bf16(
    const float* __restrict__ src, __bf16* __restrict__ dst, int R, int C) {
  __shared__ float t[32][33];
  const int rb = blockIdx.y * 32, cb = blockIdx.x * 32;
  const int c = threadIdx.x & 31;
  const int r0 = threadIdx.x >> 5;
#pragma unroll
  for (int rr = r0; rr < 32; rr += 8)
    t[rr][c] = src[(long)(rb + rr) * C + cb + c];
  __syncthreads();
#pragma unroll
  for (int rr = r0; rr < 32; rr += 8)
    dst[(long)(cb + rr) * R + rb + c] = (__bf16)t[c][rr];
}

// ---------------- CqkT (Bt layout [32][1024]) in bf16 hi/lo ----------------
__global__ __launch_bounds__(256) void k2_cqk(const float* __restrict__ Wq,
                                              const float* __restrict__ Wk,
                                              const float* __restrict__ We,
                                              __bf16* __restrict__ Cth,
                                              __bf16* __restrict__ Ctl) {
  const int gw = blockIdx.x * 4 + (threadIdx.x >> 6);  // 0..2047
  const int lane = threadIdx.x & 63;
  const int mat = gw & 1, k = gw >> 1;
  const float* Wrow = (mat ? Wk : Wq) + (long)k * H;
  const int col = lane & 15, q4 = lane >> 4;
  float acc = 0.f;
  for (int n0 = 0; n0 < 256; ++n0) {
    int n = q4 * 256 + n0;
    acc += Wrow[n] * We[n * QD + col];
  }
  acc += __shfl_xor(acc, 16);
  acc += __shfl_xor(acc, 32);
  if (lane < 16) {
    __bf16 hi = (__bf16)acc;
    __bf16 lo = (__bf16)(acc - (float)hi);
    long idx = (long)(mat * 16 + col) * H + k;
    Cth[idx] = hi;
    Ctl[idx] = lo;
  }
}

// ---------------- dvec[j] = (bq|bk)@We + be ----------------
__global__ void k2b_dvec(const float* __restrict__ bq, const float* __restrict__ bk,
                         const float* __restrict__ We, const float* __restrict__ be,
                         float* __restrict__ dvec) {
  int j = threadIdx.x;
  if (j < 32) {
    int mat = j >> 4, col = j & 15;
    const float* b = mat ? bk : bq;
    float acc = be[col];
    for (int n = 0; n < H; ++n) acc += b[n] * We[n * QD + col];
    dvec[j] = acc;
  }
}

// ---------------- embed via MFMA (hi/lo split), fused normalize ----------------
// Outputs bf16 qq/kk in [S][32] layout with zero-padded upper K half.
__global__ __launch_bounds__(256) void k3_embed_mfma(
    const __bf16* __restrict__ xh, const __bf16* __restrict__ xl,
    const __bf16* __restrict__ Cth, const __bf16* __restrict__ Ctl,
    const float* __restrict__ dvec, __bf16* __restrict__ qq32,
    __bf16* __restrict__ kk32) {
  __shared__ __bf16 Ah[32 * 64];
  __shared__ __bf16 Al[32 * 64];
  __shared__ __bf16 Bh[32 * 64];
  __shared__ __bf16 Bl[32 * 64];
  const int tid = threadIdx.x;
  const int lane = tid & 63;
  const int w = tid >> 6;
  const int rowhalf = w >> 1;  // 0/1 -> rows 0-15 / 16-31
  const int ntile = w & 1;     // 0 -> qq, 1 -> kk
  const int l15 = lane & 15, quad = lane >> 4;
  const long rowBase = (long)blockIdx.x * 32;

  const int srow = tid >> 3;                       // 0..31 (LDS row)
  const int segsw = ((tid & 7) ^ (srow & 7)) * 8;  // swizzled global k-seg
  const __bf16* agh = xh + (rowBase + srow) * H + segsw;
  const __bf16* agl = xl + (rowBase + srow) * H + segsw;
  const __bf16* bgh = Cth + (long)srow * H + segsw;
  const __bf16* bgl = Ctl + (long)srow * H + segsw;
  __bf16* lah = &Ah[srow * 64 + (tid & 7) * 8];
  __bf16* lal = &Al[srow * 64 + (tid & 7) * 8];
  __bf16* lbh = &Bh[srow * 64 + (tid & 7) * 8];
  __bf16* lbl = &Bl[srow * 64 + (tid & 7) * 8];

  f32x4 acc;
  acc[0] = 0.f; acc[1] = 0.f; acc[2] = 0.f; acc[3] = 0.f;
  const int arow = (rowhalf * 16 + l15) * 64;
  const int brow = (ntile * 16 + l15) * 64;
  const int h7 = l15 & 7;

  for (int k0 = 0; k0 < H; k0 += 64) {
    async_g2l_16(agh + k0, lah);
    async_g2l_16(agl + k0, lal);
    async_g2l_16(bgh + k0, lbh);
    async_g2l_16(bgl + k0, lbl);
    __syncthreads();
#pragma unroll
    for (int s = 0; s < 2; ++s) {
      const int slot = ((s * 4 + quad) ^ h7) * 8;
      bf16x8 fah = *(const bf16x8*)&Ah[arow + slot];
      bf16x8 fal = *(const bf16x8*)&Al[arow + slot];
      bf16x8 fbh = *(const bf16x8*)&Bh[brow + slot];
      bf16x8 fbl = *(const bf16x8*)&Bl[brow + slot];
      acc = __builtin_amdgcn_mfma_f32_16x16x32_bf16(fah, fbh, acc, 0, 0, 0);
      acc = __builtin_amdgcn_mfma_f32_16x16x32_bf16(fal, fbh, acc, 0, 0, 0);
      acc = __builtin_amdgcn_mfma_f32_16x16x32_bf16(fah, fbl, acc, 0, 0, 0);
    }
    __syncthreads();
  }

  const float dv = dvec[ntile * 16 + l15];
  __bf16* outp = ntile ? kk32 : qq32;
#pragma unroll
  for (int r = 0; r < 4; ++r) {
    float z = acc[r] + dv;
    float s2 = z * z;
    s2 += __shfl_xor(s2, 1);
    s2 += __shfl_xor(s2, 2);
    s2 += __shfl_xor(s2, 4);
    s2 += __shfl_xor(s2, 8);
    float val = z * rsqrtf(s2 + 1e-8f);
    long row = rowBase + rowhalf * 16 + quad * 4 + r;
    outp[row * 32 + l15] = (__bf16)val;
    outp[row * 32 + 16 + l15] = (__bf16)0.f;  // zero pad K 16->32
  }
}

// ---------------- fused attention, 8 waves, 128q x 256h tile ----------------
// S^T = kk@qq^T computed ONCE per (q,b) per 256h (4x less redundancy than 128h).
// S-phase: 8 waves split 128k x 128q (wave = k-half x q-quarter), b64 P writes.
// PV-phase: 8 waves = 2 q-halves x 4 h-quarters, XOR-swizzled Vlds.
#define PSTR 136  // Plds row stride bf16 (68 dwords == 4 mod 32)
__global__ __launch_bounds__(512) void fused_attn(
    const __bf16* __restrict__ qq32, const __bf16* __restrict__ kk32,
    const __bf16* __restrict__ v_t, __bf16* __restrict__ attn) {
  __shared__ __bf16 Plds[128 * PSTR];
  __shared__ __bf16 Vlds[256 * 128];
  __shared__ float rsum2[128 * 2];
  const int tid = threadIdx.x;
  const int lane = tid & 63;
  const int w = tid >> 6;  // 0..7
  const int l15 = lane & 15, quad = lane >> 4;
  const int ws_k = w & 1, ws_q = w >> 1;  // S-phase roles
  const int wp_h = w & 3, wp_q = w >> 2;  // PV-phase roles
  const int b = blockIdx.z;
  const long qbase = (long)blockIdx.y * 128;
  const long hbase = (long)blockIdx.x * 256;

  // qq B-frags: 2, constant across the k-loop
  bf16x8 bq[2];
  {
    const __bf16* qqp =
        qq32 + ((long)b * SEQ + qbase + ws_q * 32 + l15) * 32 + quad * 8;
#pragma unroll
    for (int n = 0; n < 2; ++n) bq[n] = *(const bf16x8*)(qqp + (long)n * 16 * 32);
  }
  const __bf16* kkb = kk32 + ((long)b * SEQ + ws_k * 64 + l15) * 32 + quad * 8;

  // V staging: 256h x 128k per chunk, XOR-swizzled global segment
  const int vrow = tid >> 4;   // 0..31
  const int vseg = tid & 15;
  const __bf16* vg = v_t + (long)b * H * SEQ + (hbase + vrow) * SEQ +
                     ((vseg ^ (vrow & 15)) * 8);
  __bf16* vl = &Vlds[vrow * 128 + vseg * 8];

  f32x4 acc[4][4];
#pragma unroll
  for (int i = 0; i < 4; ++i)
#pragma unroll
    for (int j = 0; j < 4; ++j) {
      acc[i][j][0] = 0.f; acc[i][j][1] = 0.f; acc[i][j][2] = 0.f; acc[i][j][3] = 0.f;
    }
  float rsPart[2] = {0.f, 0.f};

  // preload kk A-frags for chunk 0
  bf16x8 ak[4];
#pragma unroll
  for (int i = 0; i < 4; ++i) ak[i] = *(const bf16x8*)(kkb + (long)(i * 16) * 32);

  for (int k0 = 0; k0 < SEQ; k0 += 128) {
    // stage v_t[hbase:+256][k0:+128] -> Vlds (drained at the barrier)
#pragma unroll
    for (int j = 0; j < 8; ++j)
      async_g2l_16(vg + (long)k0 + (long)(j * 32) * SEQ, vl + j * 32 * 128);

    // S^T phase: this wave covers k in [ws_k*64,+64), q in [ws_q*32,+32)
#pragma unroll
    for (int i = 0; i < 4; ++i) {
#pragma unroll
      for (int n = 0; n < 2; ++n) {
        f32x4 s;
        s[0] = 0.f; s[1] = 0.f; s[2] = 0.f; s[3] = 0.f;
        s = __builtin_amdgcn_mfma_f32_16x16x32_bf16(ak[i], bq[n], s, 0, 0, 0);
        bf16x4 pw;
        float part = 0.f;
#pragma unroll
        for (int r = 0; r < 4; ++r) {
          float wgt = __expf(s[r] * s[r]);
          part += wgt;
          pw[r] = (__bf16)wgt;
        }
        rsPart[n] += part;
        *(bf16x4*)&Plds[(ws_q * 32 + n * 16 + l15) * PSTR + ws_k * 64 + i * 16 +
                        quad * 4] = pw;
      }
    }
    // prefetch next chunk's kk frags (in flight across PV)
    if (k0 + 128 < SEQ) {
#pragma unroll
      for (int i = 0; i < 4; ++i)
        ak[i] = *(const bf16x8*)(kkb + (long)(k0 + 128 + i * 16) * 32);
    }
    __syncthreads();
    // PV: acc += P[128q x 128k] @ v^T[256h x 128k]^T   (wave: 64q x 64h)
#pragma unroll
    for (int ks = 0; ks < 4; ++ks) {
      bf16x8 ap[4], bv[4];
#pragma unroll
      for (int i = 0; i < 4; ++i)
        ap[i] = *(const bf16x8*)&Plds[(wp_q * 64 + i * 16 + l15) * PSTR +
                                      ks * 32 + quad * 8];
#pragma unroll
      for (int j = 0; j < 4; ++j) {
        const int vr = wp_h * 64 + j * 16 + l15;
        const int slot = ((ks * 4 + quad) ^ l15) * 8;
        bv[j] = *(const bf16x8*)&Vlds[vr * 128 + slot];
      }
#pragma unroll
      for (int i = 0; i < 4; ++i)
#pragma unroll
        for (int j = 0; j < 4; ++j)
          acc[i][j] =
              __builtin_amdgcn_mfma_f32_16x16x32_bf16(ap[i], bv[j], acc[i][j], 0, 0, 0);
    }
    __syncthreads();
  }

  // rowsum: reduce lane partials over quads, combine two k-halves via LDS
#pragma unroll
  for (int n = 0; n < 2; ++n) {
    float vs = rsPart[n];
    vs += __shfl_xor(vs, 16);
    vs += __shfl_xor(vs, 32);
    if (lane < 16) rsum2[(ws_q * 32 + n * 16 + l15) * 2 + ws_k] = vs;
  }
  __syncthreads();

  float rinv[4][4];
#pragma unroll
  for (int i = 0; i < 4; ++i)
#pragma unroll
    for (int r = 0; r < 4; ++r) {
      int row = wp_q * 64 + i * 16 + quad * 4 + r;
      rinv[i][r] = 1.0f / (rsum2[row * 2] + rsum2[row * 2 + 1]);
    }

  __bf16* ob = attn + ((long)b * SEQ + qbase) * H + hbase;
#pragma unroll
  for (int i = 0; i < 4; ++i)
#pragma unroll
    for (int j = 0; j < 4; ++j) {
      const int colL = wp_h * 64 + j * 16 + l15;
#pragma unroll
      for (int r = 0; r < 4; ++r) {
        const int rowL = wp_q * 64 + i * 16 + quad * 4 + r;
        ob[(long)rowL * H + colL] = (__bf16)(acc[i][j][r] * rinv[i][r]);
      }
    }
}

// ---------------- m97-style GEMM + XOR-swizzled LDS: C = A @ Bt^T (+bias) ----
// OUTMODE: 0 = fp32 row-major, 1 = bf16 row-major, 2 = bf16 transposed batched
//          (Cout layout [BATCH][N][SEQ], rows are per-batch: row = b*SEQ + rb)
template <int OUTMODE, int HASBIAS>
__global__ __launch_bounds__(256) void gemm_bt(
    const __bf16* __restrict__ A, const __bf16* __restrict__ Bt,
    void* __restrict__ Cout, const float* __restrict__ bias, int M, int N, int K) {
  __shared__ __bf16 Alds[128 * 64];
  __shared__ __bf16 Blds[128 * 64];
  const int tid = threadIdx.x;
  const int lane = tid & 63;
  const int w = tid >> 6;
  const int wm = w >> 1, wn = w & 1;
  const int l15 = lane & 15, quad = lane >> 4;
  const long rowBase = (long)blockIdx.y * 128;
  const long colBase = (long)blockIdx.x * 128;

  const int srow = lane >> 3;                 // 0..7
  const int segsw = ((lane & 7) ^ srow) * 8;  // swizzled global k-seg

  const __bf16* ag[4];
  const __bf16* bg[4];
  __bf16* as_[4];
  __bf16* bs_[4];
#pragma unroll
  for (int j = 0; j < 4; ++j) {
    int r = j * 32 + w * 8;
    ag[j] = A + (rowBase + r + srow) * (long)K + segsw;
    bg[j] = Bt + (colBase + r + srow) * (long)K + segsw;
    as_[j] = &Alds[r * 64 + (lane & 7) * 8];
    bs_[j] = &Blds[r * 64 + (lane & 7) * 8];
  }

  f32x4 acc[4][4];
#pragma unroll
  for (int i = 0; i < 4; ++i)
#pragma unroll
    for (int j = 0; j < 4; ++j) {
      acc[i][j][0] = 0.f; acc[i][j][1] = 0.f; acc[i][j][2] = 0.f; acc[i][j][3] = 0.f;
    }

  const int h7 = l15 & 7;

  for (int k0 = 0; k0 < K; k0 += 64) {
#pragma unroll
    for (int j = 0; j < 4; ++j) {
      async_g2l_16(ag[j], as_[j]);
      async_g2l_16(bg[j], bs_[j]);
      ag[j] += 64;
      bg[j] += 64;
    }
    __syncthreads();
#pragma unroll
    for (int s = 0; s < 2; ++s) {
      const int slot = ((s * 4 + quad) ^ h7) * 8;
      bf16x8 af[4], bfv[4];
#pragma unroll
      for (int i = 0; i < 4; ++i) {
        af[i] = *(const bf16x8*)&Alds[(wm * 64 + i * 16 + l15) * 64 + slot];
        bfv[i] = *(const bf16x8*)&Blds[(wn * 64 + i * 16 + l15) * 64 + slot];
      }
#pragma unroll
      for (int i = 0; i < 4; ++i)
#pragma unroll
        for (int j = 0; j < 4; ++j)
          acc[i][j] =
              __builtin_amdgcn_mfma_f32_16x16x32_bf16(af[i], bfv[j], acc[i][j], 0, 0, 0);
    }
    __syncthreads();
  }

  const long crow0 = rowBase + wm * 64 + quad * 4;
  const long ccol0 = colBase + wn * 64 + l15;
#pragma unroll
  for (int i = 0; i < 4; ++i) {
#pragma unroll
    for (int j = 0; j < 4; ++j) {
      long col = ccol0 + j * 16;
      float bb = HASBIAS ? bias[col] : 0.f;
      if (OUTMODE == 2) {
        long row0 = crow0 + i * 16;          // 4 consecutive rows, same batch
        int bz = (int)(row0 >> 11);          // row / SEQ
        long rb = row0 & (SEQ - 1);
        bf16x4 pv;
#pragma unroll
        for (int r = 0; r < 4; ++r) pv[r] = (__bf16)(acc[i][j][r] + bb);
        *(bf16x4*)&((__bf16*)Cout)[((long)bz * N + col) * SEQ + rb] = pv;
      } else {
#pragma unroll
        for (int r = 0; r < 4; ++r) {
          long row = crow0 + i * 16 + r;
          float val = acc[i][j][r] + bb;
          if (OUTMODE == 0)
            ((float*)Cout)[row * N + col] = val;
          else
            ((__bf16*)Cout)[row * N + col] = (__bf16)val;
        }
      }
    }
  }
}

extern "C" void kernel_launch(void* const* d_in, const int* in_sizes, int n_in,
                              void* d_out, int out_size, void* d_ws, size_t ws_size,
                              hipStream_t stream) {
  const float* x = (const float*)d_in[0];
  const float* Wq = (const float*)d_in[1];
  const float* bq = (const float*)d_in[2];
  const float* Wk = (const float*)d_in[3];
  const float* bk = (const float*)d_in[4];
  const float* Wv = (const float*)d_in[5];
  const float* bv = (const float*)d_in[6];
  const float* We = (const float*)d_in[7];
  const float* be = (const float*)d_in[8];
  const float* Wo = (const float*)d_in[9];
  const float* bo = (const float*)d_in[10];
  float* out = (float*)d_out;

  char* ws = (char*)d_ws;
  size_t o = 0;
  auto alloc = [&](size_t n) {
    size_t r = o;
    o += (n + 255) & ~(size_t)255;
    return r;
  };
  __bf16* xbf = (__bf16*)(ws + alloc((size_t)MROWS * H * 2));  // x hi
  __bf16* v_t = (__bf16*)(ws + alloc((size_t)MROWS * H * 2));  // v^T [B][H][S]
  __bf16* attn = (__bf16*)(ws + alloc((size_t)MROWS * H * 2));
  __bf16* Wvt = (__bf16*)(ws + alloc((size_t)H * H * 2));
  __bf16* Wot = (__bf16*)(ws + alloc((size_t)H * H * 2));
  __bf16* Cth = (__bf16*)(ws + alloc((size_t)32 * H * 2));
  __bf16* Ctl = (__bf16*)(ws + alloc((size_t)32 * H * 2));
  float* dvec = (float*)(ws + alloc(32 * 4));
  __bf16* qq32 = (__bf16*)(ws + alloc((size_t)MROWS * 32 * 2));
  __bf16* kk32 = (__bf16*)(ws + alloc((size_t)MROWS * 32 * 2));
  // Alias (stream-ordered lifetime separation):
  __bf16* xlo = attn;  // x lo part: dead before attn is written (fused_attn)
  if (ws_size < o) return;

  // 1) x -> bf16 hi/lo split
  cvt_split<<<MROWS * H / 1024, 256, 0, stream>>>(x, xbf, xlo, MROWS * H);
  // 2) Wv^T, Wo^T as bf16
  transpose_cvt_f32_bf16<<<dim3(32, 32), 256, 0, stream>>>(Wv, Wvt, H, H);
  transpose_cvt_f32_bf16<<<dim3(32, 32), 256, 0, stream>>>(Wo, Wot, H, H);
  // 3) collapsed embed matrices (bf16 hi/lo, Bt layout) + bias fold
  k2_cqk<<<512, 256, 0, stream>>>(Wq, Wk, We, Cth, Ctl);
  k2b_dvec<<<1, 64, 0, stream>>>(bq, bk, We, be, dvec);
  // 4) unit-norm quantum embeds via MFMA -> bf16 [S][32] zero-padded
  k3_embed_mfma<<<MROWS / 32, 256, 0, stream>>>(xbf, xlo, Cth, Ctl, dvec, qq32, kk32);
  // 5) v = x@Wv + bv, written TRANSPOSED per batch -> v_t[b][h][s]
  gemm_bt<2, 1><<<dim3(8, 64), 256, 0, stream>>>(xbf, Wvt, v_t, bv, MROWS, H, H);
  // 6) fused: S^T once per 256h -> exp(S^2) -> P@v/rowsum  (bf16 out)
  fused_attn<<<dim3(4, 16, BATCH), 512, 0, stream>>>(qq32, kk32, v_t, attn);
  // 7) out = attended @ Wo + bo  (fp32 out)
  gemm_bt<0, 1><<<dim3(8, 64), 256, 0, stream>>>(attn, Wot, out, bo, MROWS, H, H);
}